// Round 4
// baseline (1054.862 us; speedup 1.0000x reference)
//
#include <hip/hip_runtime.h>
#include <hip/hip_bf16.h>
#include <math.h>

#define D_DIM 1024
#define F_DIM 2816
#define E_NUM 8

#define BM 128
#define BN 64
#define BK 64

typedef __attribute__((ext_vector_type(4))) float f32x4;
typedef __attribute__((ext_vector_type(8))) short short8;

__device__ __forceinline__ unsigned short f2bf(float f) {
    unsigned u = __float_as_uint(f);
    u = (u + 0x7FFFu + ((u >> 16) & 1u)) >> 16;
    return (unsigned short)u;
}

__device__ __forceinline__ float gelu_erf(float z) {
    return 0.5f * z * (1.0f + erff(z * 0.70710678118654752f));
}

// XOR swizzle on the LDS READ side: 128B rows, 16B blocks permuted by row&7.
// WRITE side achieves the same layout via pre-swizzled GLOBAL source addresses
// fed to global_load_lds (LDS dest stays linear).
__device__ __forceinline__ int swz(int row, int kb) {
    return row * 128 + (kb ^ ((row & 7) << 4));
}

__device__ __forceinline__ uint4 pack8(const unsigned short* h) {
    uint4 r;
    r.x = (unsigned)h[0] | ((unsigned)h[1] << 16);
    r.y = (unsigned)h[2] | ((unsigned)h[3] << 16);
    r.z = (unsigned)h[4] | ((unsigned)h[5] << 16);
    r.w = (unsigned)h[6] | ((unsigned)h[7] << 16);
    return r;
}

// async global->LDS, 16B per lane; lds must be wave-uniform, g is per-lane
__device__ __forceinline__ void gload16(const void* g, void* l) {
    __builtin_amdgcn_global_load_lds(
        (const __attribute__((address_space(1))) unsigned int*)g,
        (__attribute__((address_space(3))) unsigned int*)l,
        16, 0, 0);
}

// ---------------- weight transpose + fp32->bf16 convert ----------------
// src [E][R][C] fp32 -> dst [E][C][R] bf16. grid (C/64, R/64, E), 256 thr.
__global__ __launch_bounds__(256) void transpose_cvt_kernel(
    const float* __restrict__ src, unsigned short* __restrict__ dst, int R, int C)
{
    __shared__ float tile[64][65];
    int e = blockIdx.z;
    const float* s = src + (size_t)e * R * C;
    unsigned short* d = dst + (size_t)e * R * C;
    int c0 = blockIdx.x * 64;
    int r0 = blockIdx.y * 64;
    int tid = threadIdx.x;
#pragma unroll
    for (int i = 0; i < 4; ++i) {
        int idx = tid + 256 * i;
        int r = idx >> 4, cc = (idx & 15) * 4;
        float4 v = *(const float4*)(s + (size_t)(r0 + r) * C + c0 + cc);
        tile[r][cc] = v.x; tile[r][cc + 1] = v.y; tile[r][cc + 2] = v.z; tile[r][cc + 3] = v.w;
    }
    __syncthreads();
#pragma unroll
    for (int i = 0; i < 2; ++i) {
        int idx = tid + 256 * i;
        int c = idx >> 3, rr = (idx & 7) * 8;
        unsigned short h[8];
#pragma unroll
        for (int j = 0; j < 8; ++j) h[j] = f2bf(tile[rr + j][c]);
        *(uint4*)(d + (size_t)(c0 + c) * R + r0 + rr) = pack8(h);
    }
}

// ---------------- router: scores, softmax, top-2, x->bf16 ----------------
__global__ __launch_bounds__(64) void router_kernel(
    const float* __restrict__ x, const float* __restrict__ rw,
    unsigned short* __restrict__ xbf, int* __restrict__ tk_idx,
    float* __restrict__ tk_w, int* __restrict__ counts)
{
    int t = blockIdx.x;
    int lane = threadIdx.x;
    const float* xr = x + (size_t)t * D_DIM;
    float acc[E_NUM];
#pragma unroll
    for (int e = 0; e < E_NUM; ++e) acc[e] = 0.f;
#pragma unroll
    for (int i = 0; i < D_DIM / 64; ++i) {
        int d = lane + 64 * i;
        float xv = xr[d];
        xbf[(size_t)t * D_DIM + d] = f2bf(xv);
        const float* rp = rw + (size_t)d * E_NUM;
#pragma unroll
        for (int e = 0; e < E_NUM; ++e) acc[e] += xv * rp[e];
    }
#pragma unroll
    for (int e = 0; e < E_NUM; ++e) {
#pragma unroll
        for (int s = 32; s > 0; s >>= 1) acc[e] += __shfl_xor(acc[e], s, 64);
    }
    float mx = acc[0];
#pragma unroll
    for (int e = 1; e < E_NUM; ++e) mx = fmaxf(mx, acc[e]);
    float p[E_NUM], se = 0.f;
#pragma unroll
    for (int e = 0; e < E_NUM; ++e) { p[e] = expf(acc[e] - mx); se += p[e]; }
    float inv = 1.f / se;
    int e1 = 0;
#pragma unroll
    for (int e = 1; e < E_NUM; ++e) if (p[e] > p[e1]) e1 = e;
    int e2 = (e1 == 0) ? 1 : 0;
#pragma unroll
    for (int e = 0; e < E_NUM; ++e) if (e != e1 && p[e] > p[e2]) e2 = e;
    if (lane == 0) {
        tk_idx[2 * t] = e1; tk_idx[2 * t + 1] = e2;
        tk_w[2 * t] = p[e1] * inv; tk_w[2 * t + 1] = p[e2] * inv;
        atomicAdd(&counts[e1], 1);
        atomicAdd(&counts[e2], 1);
    }
}

// ---------------- scan: offsets + tile map ----------------
__global__ void scan_kernel(const int* __restrict__ counts, int* __restrict__ offsets,
                            int* __restrict__ tile_e, int* __restrict__ tile_row,
                            int* __restrict__ n_mt)
{
    if (threadIdx.x != 0) return;
    int off = 0, nt = 0;
    for (int e = 0; e < E_NUM; ++e) {
        offsets[e] = off;
        int ne = counts[e];
        int nti = (ne + BM - 1) / BM;
        for (int i = 0; i < nti; ++i) { tile_e[nt] = e; tile_row[nt] = off + i * BM; ++nt; }
        off += ne;
    }
    offsets[E_NUM] = off;
    *n_mt = nt;
}

// ---------------- compact: deterministic token-ordered pair lists ----------------
__global__ __launch_bounds__(256) void compact_kernel(
    const int* __restrict__ tk_idx, const int* __restrict__ offsets,
    int* __restrict__ pair_token, int* __restrict__ pair_pos, int T)
{
    int e = blockIdx.x;
    int tid = threadIdx.x;
    __shared__ int s[256];
    __shared__ int running;
    if (tid == 0) running = 0;
    __syncthreads();
    int base0 = offsets[e];
    for (int base = 0; base < T; base += 256) {
        int t = base + tid;
        int flag = 0, slot = -1;
        if (t < T) {
            int i0 = tk_idx[2 * t], i1 = tk_idx[2 * t + 1];
            slot = (i0 == e) ? 0 : ((i1 == e) ? 1 : -1);
            flag = (slot >= 0) ? 1 : 0;
        }
        s[tid] = flag;
        __syncthreads();
        for (int d = 1; d < 256; d <<= 1) {
            int v = (tid >= d) ? s[tid - d] : 0;
            __syncthreads();
            s[tid] += v;
            __syncthreads();
        }
        int total = s[255];
        int run = running;
        if (flag) {
            int pos = base0 + run + s[tid] - 1;
            pair_token[pos] = t;
            pair_pos[2 * t + slot] = pos;
        }
        __syncthreads();
        if (tid == 0) running += total;
        __syncthreads();
    }
}

// ---------------- grouped GEMM1 + GLU: h = gelu(x@w1) * (x@v1), bf16 out ----------------
// m97-style single-buffered K-loop: STAGE -> barrier(vmcnt drain) -> MFMA -> barrier.
// 32KB LDS -> 5 blocks/CU; TLP across blocks hides the barrier drain.
__global__ __launch_bounds__(256, 5) void gemm1_glu_kernel(
    const unsigned short* __restrict__ xbf,
    const unsigned short* __restrict__ w1t, const unsigned short* __restrict__ v1t,
    const int* __restrict__ pair_token, const int* __restrict__ offsets,
    const int* __restrict__ tile_e, const int* __restrict__ tile_row,
    const int* __restrict__ n_mt,
    unsigned short* __restrict__ hbf)
{
    int mt = blockIdx.x;
    if (mt >= *n_mt) return;
    int e = tile_e[mt];
    int row0 = tile_row[mt];
    int end = offsets[e + 1];
    int n0 = blockIdx.y * BN;

    __shared__ __align__(16) unsigned short As[BM * BK];   // 16KB
    __shared__ __align__(16) unsigned short B0s[BN * BK];  // 8KB
    __shared__ __align__(16) unsigned short B1s[BN * BK];  // 8KB

    int tid = threadIdx.x;
    int lane = tid & 63;
    int wid = tid >> 6;
    int wr = wid >> 1, wc = wid & 1;
    int sub = lane >> 3;
    // pre-swizzled source offset within a 128B row-block (constant per lane)
    int srcoff = (((lane & 7) ^ sub) << 4);

    const unsigned short* W0 = w1t + (size_t)e * D_DIM * F_DIM;
    const unsigned short* W1 = v1t + (size_t)e * D_DIM * F_DIM;

    // per-lane global source pointers (advance by 128B per K-step)
    const char* aptr[4];
#pragma unroll
    for (int i = 0; i < 4; ++i) {
        int row = (wid * 4 + i) * 8 + sub;
        int p = row0 + row;
        if (p >= end) p = end - 1;   // garbage rows only feed masked outputs
        aptr[i] = (const char*)(xbf + (size_t)pair_token[p] * D_DIM) + srcoff;
    }
    const char* b0ptr[2];
    const char* b1ptr[2];
#pragma unroll
    for (int i = 0; i < 2; ++i) {
        int n = (wid * 2 + i) * 8 + sub;
        b0ptr[i] = (const char*)(W0 + (size_t)(n0 + n) * D_DIM) + srcoff;
        b1ptr[i] = (const char*)(W1 + (size_t)(n0 + n) * D_DIM) + srcoff;
    }

    f32x4 acc[2][4][2];
#pragma unroll
    for (int a = 0; a < 2; ++a)
#pragma unroll
        for (int m = 0; m < 4; ++m)
#pragma unroll
            for (int n = 0; n < 2; ++n) acc[a][m][n] = (f32x4){0.f, 0.f, 0.f, 0.f};

    auto STAGE = [&]() {
#pragma unroll
        for (int i = 0; i < 4; ++i) {
            gload16(aptr[i], (char*)As + (wid * 4 + i) * 1024);
            aptr[i] += 128;
        }
#pragma unroll
        for (int i = 0; i < 2; ++i) {
            gload16(b0ptr[i], (char*)B0s + (wid * 2 + i) * 1024);
            b0ptr[i] += 128;
            gload16(b1ptr[i], (char*)B1s + (wid * 2 + i) * 1024);
            b1ptr[i] += 128;
        }
    };

    const int NT = D_DIM / BK;
    for (int kt = 0; kt < NT; ++kt) {
        STAGE();
        __syncthreads();                 // vmcnt(0) drain -> LDS ready
#pragma unroll
        for (int kk = 0; kk < 2; ++kk) {
            short8 af[4];
#pragma unroll
            for (int m = 0; m < 4; ++m) {
                int row = wr * 64 + m * 16 + (lane & 15);
                int kb = kk * 64 + (lane >> 4) * 16;
                af[m] = *(const short8*)((char*)As + swz(row, kb));
            }
            short8 bf0[2], bf1[2];
#pragma unroll
            for (int n = 0; n < 2; ++n) {
                int rn = wc * 32 + n * 16 + (lane & 15);
                int kb = kk * 64 + (lane >> 4) * 16;
                bf0[n] = *(const short8*)((char*)B0s + swz(rn, kb));
                bf1[n] = *(const short8*)((char*)B1s + swz(rn, kb));
            }
#pragma unroll
            for (int m = 0; m < 4; ++m)
#pragma unroll
                for (int n = 0; n < 2; ++n) {
                    acc[0][m][n] = __builtin_amdgcn_mfma_f32_16x16x32_bf16(af[m], bf0[n], acc[0][m][n], 0, 0, 0);
                    acc[1][m][n] = __builtin_amdgcn_mfma_f32_16x16x32_bf16(af[m], bf1[n], acc[1][m][n], 0, 0, 0);
                }
        }
        __syncthreads();                 // reads done before next STAGE overwrites
    }
#pragma unroll
    for (int m = 0; m < 4; ++m) {
#pragma unroll
        for (int j = 0; j < 4; ++j) {
            int rl = wr * 64 + m * 16 + (lane >> 4) * 4 + j;
            int p = row0 + rl;
            if (p < end) {
#pragma unroll
                for (int n = 0; n < 2; ++n) {
                    float z1 = acc[0][m][n][j];
                    float z2 = acc[1][m][n][j];
                    float hv = gelu_erf(z1) * z2;
                    hbf[(size_t)p * F_DIM + n0 + wc * 32 + n * 16 + (lane & 15)] = f2bf(hv);
                }
            }
        }
    }
}

// ---------------- grouped GEMM2: y = h @ w2[e], fp32 per-pair out ----------------
// A: hbf [P][F]; B: w2t [E][D][F] bf16. Single-buffered, 24KB LDS -> 6 blocks/CU.
__global__ __launch_bounds__(256, 6) void gemm2_kernel(
    const unsigned short* __restrict__ hbf,
    const unsigned short* __restrict__ w2t,
    const int* __restrict__ offsets,
    const int* __restrict__ tile_e, const int* __restrict__ tile_row,
    const int* __restrict__ n_mt,
    float* __restrict__ ypair)
{
    int mt = blockIdx.x;
    if (mt >= *n_mt) return;
    int e = tile_e[mt];
    int row0 = tile_row[mt];
    int end = offsets[e + 1];
    int n0 = blockIdx.y * BN;

    __shared__ __align__(16) unsigned short As[BM * BK];  // 16KB
    __shared__ __align__(16) unsigned short Bs[BN * BK];  // 8KB

    int tid = threadIdx.x;
    int lane = tid & 63;
    int wid = tid >> 6;
    int wr = wid >> 1, wc = wid & 1;
    int sub = lane >> 3;
    int srcoff = (((lane & 7) ^ sub) << 4);

    const unsigned short* W = w2t + (size_t)e * D_DIM * F_DIM;

    const char* aptr[4];
#pragma unroll
    for (int i = 0; i < 4; ++i) {
        int row = (wid * 4 + i) * 8 + sub;
        int p = row0 + row;
        if (p >= end) p = end - 1;
        aptr[i] = (const char*)(hbf + (size_t)p * F_DIM) + srcoff;
    }
    const char* bptr[2];
#pragma unroll
    for (int i = 0; i < 2; ++i) {
        int n = (wid * 2 + i) * 8 + sub;
        bptr[i] = (const char*)(W + (size_t)(n0 + n) * F_DIM) + srcoff;
    }

    f32x4 acc[4][2];
#pragma unroll
    for (int m = 0; m < 4; ++m)
#pragma unroll
        for (int n = 0; n < 2; ++n) acc[m][n] = (f32x4){0.f, 0.f, 0.f, 0.f};

    auto STAGE = [&]() {
#pragma unroll
        for (int i = 0; i < 4; ++i) {
            gload16(aptr[i], (char*)As + (wid * 4 + i) * 1024);
            aptr[i] += 128;
        }
#pragma unroll
        for (int i = 0; i < 2; ++i) {
            gload16(bptr[i], (char*)Bs + (wid * 2 + i) * 1024);
            bptr[i] += 128;
        }
    };

    const int NT = F_DIM / BK;
    for (int kt = 0; kt < NT; ++kt) {
        STAGE();
        __syncthreads();
#pragma unroll
        for (int kk = 0; kk < 2; ++kk) {
            short8 af[4];
#pragma unroll
            for (int m = 0; m < 4; ++m) {
                int row = wr * 64 + m * 16 + (lane & 15);
                int kb = kk * 64 + (lane >> 4) * 16;
                af[m] = *(const short8*)((char*)As + swz(row, kb));
            }
            short8 bfr[2];
#pragma unroll
            for (int n = 0; n < 2; ++n) {
                int rn = wc * 32 + n * 16 + (lane & 15);
                int kb = kk * 64 + (lane >> 4) * 16;
                bfr[n] = *(const short8*)((char*)Bs + swz(rn, kb));
            }
#pragma unroll
            for (int m = 0; m < 4; ++m)
#pragma unroll
                for (int n = 0; n < 2; ++n)
                    acc[m][n] = __builtin_amdgcn_mfma_f32_16x16x32_bf16(af[m], bfr[n], acc[m][n], 0, 0, 0);
        }
        __syncthreads();
    }
#pragma unroll
    for (int m = 0; m < 4; ++m) {
#pragma unroll
        for (int j = 0; j < 4; ++j) {
            int rl = wr * 64 + m * 16 + (lane >> 4) * 4 + j;
            int p = row0 + rl;
            if (p < end) {
#pragma unroll
                for (int n = 0; n < 2; ++n)
                    ypair[(size_t)p * D_DIM + n0 + wc * 32 + n * 16 + (lane & 15)] = acc[m][n][j];
            }
        }
    }
}

// ---------------- combine: out = bias + w0*y[p0] + w1*y[p1] ----------------
__global__ __launch_bounds__(256) void combine_kernel(
    const float* __restrict__ ypair, const int* __restrict__ pair_pos,
    const float* __restrict__ tk_w, const float* __restrict__ bias,
    float* __restrict__ out, int total)
{
    int idx = blockIdx.x * 256 + threadIdx.x;
    if (idx >= total) return;
    int t = idx >> 10;
    int d = idx & (D_DIM - 1);
    int p0 = pair_pos[2 * t], p1 = pair_pos[2 * t + 1];
    float r = bias[d] + tk_w[2 * t] * ypair[(size_t)p0 * D_DIM + d]
                      + tk_w[2 * t + 1] * ypair[(size_t)p1 * D_DIM + d];
    out[idx] = r;
}

__global__ void ws_too_small_kernel(float* out, int n) {
    int i = blockIdx.x * 256 + threadIdx.x;
    if (i < n) out[i] = 12345.0f;
}

extern "C" void kernel_launch(void* const* d_in, const int* in_sizes, int n_in,
                              void* d_out, int out_size, void* d_ws, size_t ws_size,
                              hipStream_t stream) {
    const float* x    = (const float*)d_in[0];
    const float* rw   = (const float*)d_in[1];
    const float* w1   = (const float*)d_in[2];
    const float* v1   = (const float*)d_in[3];
    const float* w2   = (const float*)d_in[4];
    const float* bias = (const float*)d_in[5];
    float* out = (float*)d_out;

    int T = in_sizes[0] / D_DIM;      // 4096
    int P = 2 * T;
    int maxMT = P / BM + E_NUM;       // 72

    char* p = (char*)d_ws;
    char* ws_end = p + ws_size;
    auto alloc = [&](size_t bytes) {
        char* r = p;
        p += (bytes + 255) & ~(size_t)255;
        return r;
    };
    unsigned short* xbf   = (unsigned short*)alloc((size_t)T * D_DIM * 2);
    int*   tk_idx     = (int*)alloc((size_t)T * 2 * 4);
    float* tk_w       = (float*)alloc((size_t)T * 2 * 4);
    int*   counts     = (int*)alloc(E_NUM * 4);
    int*   offsets    = (int*)alloc((E_NUM + 1) * 4);
    int*   tile_e     = (int*)alloc(maxMT * 4);
    int*   tile_row   = (int*)alloc(maxMT * 4);
    int*   n_mt       = (int*)alloc(4);
    int*   pair_token = (int*)alloc((size_t)P * 4);
    int*   pair_pos   = (int*)alloc((size_t)P * 4);
    unsigned short* hbf = (unsigned short*)alloc((size_t)P * F_DIM * 2);
    float* ypair      = (float*)alloc((size_t)P * D_DIM * 4);
    unsigned short* w1t = (unsigned short*)alloc((size_t)E_NUM * D_DIM * F_DIM * 2);
    unsigned short* v1t = (unsigned short*)alloc((size_t)E_NUM * D_DIM * F_DIM * 2);
    unsigned short* w2t = (unsigned short*)alloc((size_t)E_NUM * D_DIM * F_DIM * 2);

    if (p > ws_end) {
        ws_too_small_kernel<<<(out_size + 255) / 256, 256, 0, stream>>>(out, out_size);
        return;
    }

    hipMemsetAsync(counts, 0, E_NUM * 4, stream);
    // weight transpose+convert: w1,v1 [E][D][F] -> [E][F][D]; w2 [E][F][D] -> [E][D][F]
    transpose_cvt_kernel<<<dim3(F_DIM / 64, D_DIM / 64, E_NUM), 256, 0, stream>>>(w1, w1t, D_DIM, F_DIM);
    transpose_cvt_kernel<<<dim3(F_DIM / 64, D_DIM / 64, E_NUM), 256, 0, stream>>>(v1, v1t, D_DIM, F_DIM);
    transpose_cvt_kernel<<<dim3(D_DIM / 64, F_DIM / 64, E_NUM), 256, 0, stream>>>(w2, w2t, F_DIM, D_DIM);
    router_kernel<<<T, 64, 0, stream>>>(x, rw, xbf, tk_idx, tk_w, counts);
    scan_kernel<<<1, 64, 0, stream>>>(counts, offsets, tile_e, tile_row, n_mt);
    compact_kernel<<<E_NUM, 256, 0, stream>>>(tk_idx, offsets, pair_token, pair_pos, T);
    gemm1_glu_kernel<<<dim3(maxMT, F_DIM / BN), 256, 0, stream>>>(
        xbf, w1t, v1t, pair_token, offsets, tile_e, tile_row, n_mt, hbf);
    gemm2_kernel<<<dim3(maxMT, D_DIM / BN), 256, 0, stream>>>(
        hbf, w2t, offsets, tile_e, tile_row, n_mt, ypair);
    combine_kernel<<<(T * D_DIM + 255) / 256, 256, 0, stream>>>(
        ypair, pair_pos, tk_w, bias, out, T * D_DIM);
}

// Round 5
// 482.006 us; speedup vs baseline: 2.1885x; 2.1885x over previous
//
#include <hip/hip_runtime.h>
#include <hip/hip_bf16.h>
#include <math.h>

#define D_DIM 1024
#define F_DIM 2816
#define E_NUM 8

#define BM 128
#define BN 64
#define BK 64

typedef __attribute__((ext_vector_type(4))) float f32x4;
typedef __attribute__((ext_vector_type(8))) short short8;

__device__ __forceinline__ unsigned short f2bf(float f) {
    unsigned u = __float_as_uint(f);
    u = (u + 0x7FFFu + ((u >> 16) & 1u)) >> 16;
    return (unsigned short)u;
}

__device__ __forceinline__ float gelu_erf(float z) {
    return 0.5f * z * (1.0f + erff(z * 0.70710678118654752f));
}

// XOR swizzle on the LDS READ side: 128B rows, 16B blocks permuted by row&7.
// WRITE side achieves the same layout via pre-swizzled GLOBAL source addresses
// fed to global_load_lds (LDS dest stays linear).
__device__ __forceinline__ int swz(int row, int kb) {
    return row * 128 + (kb ^ ((row & 7) << 4));
}

__device__ __forceinline__ uint4 pack8(const unsigned short* h) {
    uint4 r;
    r.x = (unsigned)h[0] | ((unsigned)h[1] << 16);
    r.y = (unsigned)h[2] | ((unsigned)h[3] << 16);
    r.z = (unsigned)h[4] | ((unsigned)h[5] << 16);
    r.w = (unsigned)h[6] | ((unsigned)h[7] << 16);
    return r;
}

// async global->LDS, 16B per lane; lds must be wave-uniform, g is per-lane
__device__ __forceinline__ void gload16(const void* g, void* l) {
    __builtin_amdgcn_global_load_lds(
        (const __attribute__((address_space(1))) unsigned int*)g,
        (__attribute__((address_space(3))) unsigned int*)l,
        16, 0, 0);
}

// ---------------- weight transpose + fp32->bf16 convert ----------------
// src [E][R][C] fp32 -> dst [E][C][R] bf16. grid (C/64, R/64, E), 256 thr.
__global__ __launch_bounds__(256) void transpose_cvt_kernel(
    const float* __restrict__ src, unsigned short* __restrict__ dst, int R, int C)
{
    __shared__ float tile[64][65];
    int e = blockIdx.z;
    const float* s = src + (size_t)e * R * C;
    unsigned short* d = dst + (size_t)e * R * C;
    int c0 = blockIdx.x * 64;
    int r0 = blockIdx.y * 64;
    int tid = threadIdx.x;
#pragma unroll
    for (int i = 0; i < 4; ++i) {
        int idx = tid + 256 * i;
        int r = idx >> 4, cc = (idx & 15) * 4;
        float4 v = *(const float4*)(s + (size_t)(r0 + r) * C + c0 + cc);
        tile[r][cc] = v.x; tile[r][cc + 1] = v.y; tile[r][cc + 2] = v.z; tile[r][cc + 3] = v.w;
    }
    __syncthreads();
#pragma unroll
    for (int i = 0; i < 2; ++i) {
        int idx = tid + 256 * i;
        int c = idx >> 3, rr = (idx & 7) * 8;
        unsigned short h[8];
#pragma unroll
        for (int j = 0; j < 8; ++j) h[j] = f2bf(tile[rr + j][c]);
        *(uint4*)(d + (size_t)(c0 + c) * R + r0 + rr) = pack8(h);
    }
}

// ---------------- router: scores, softmax, top-2, x->bf16 ----------------
__global__ __launch_bounds__(64) void router_kernel(
    const float* __restrict__ x, const float* __restrict__ rw,
    unsigned short* __restrict__ xbf, int* __restrict__ tk_idx,
    float* __restrict__ tk_w, int* __restrict__ counts)
{
    int t = blockIdx.x;
    int lane = threadIdx.x;
    const float* xr = x + (size_t)t * D_DIM;
    float acc[E_NUM];
#pragma unroll
    for (int e = 0; e < E_NUM; ++e) acc[e] = 0.f;
#pragma unroll
    for (int i = 0; i < D_DIM / 64; ++i) {
        int d = lane + 64 * i;
        float xv = xr[d];
        xbf[(size_t)t * D_DIM + d] = f2bf(xv);
        const float* rp = rw + (size_t)d * E_NUM;
#pragma unroll
        for (int e = 0; e < E_NUM; ++e) acc[e] += xv * rp[e];
    }
#pragma unroll
    for (int e = 0; e < E_NUM; ++e) {
#pragma unroll
        for (int s = 32; s > 0; s >>= 1) acc[e] += __shfl_xor(acc[e], s, 64);
    }
    float mx = acc[0];
#pragma unroll
    for (int e = 1; e < E_NUM; ++e) mx = fmaxf(mx, acc[e]);
    float p[E_NUM], se = 0.f;
#pragma unroll
    for (int e = 0; e < E_NUM; ++e) { p[e] = expf(acc[e] - mx); se += p[e]; }
    float inv = 1.f / se;
    int e1 = 0;
#pragma unroll
    for (int e = 1; e < E_NUM; ++e) if (p[e] > p[e1]) e1 = e;
    int e2 = (e1 == 0) ? 1 : 0;
#pragma unroll
    for (int e = 0; e < E_NUM; ++e) if (e != e1 && p[e] > p[e2]) e2 = e;
    if (lane == 0) {
        tk_idx[2 * t] = e1; tk_idx[2 * t + 1] = e2;
        tk_w[2 * t] = p[e1] * inv; tk_w[2 * t + 1] = p[e2] * inv;
        atomicAdd(&counts[e1], 1);
        atomicAdd(&counts[e2], 1);
    }
}

// ---------------- scan: offsets + tile map ----------------
__global__ void scan_kernel(const int* __restrict__ counts, int* __restrict__ offsets,
                            int* __restrict__ tile_e, int* __restrict__ tile_row,
                            int* __restrict__ n_mt)
{
    if (threadIdx.x != 0) return;
    int off = 0, nt = 0;
    for (int e = 0; e < E_NUM; ++e) {
        offsets[e] = off;
        int ne = counts[e];
        int nti = (ne + BM - 1) / BM;
        for (int i = 0; i < nti; ++i) { tile_e[nt] = e; tile_row[nt] = off + i * BM; ++nt; }
        off += ne;
    }
    offsets[E_NUM] = off;
    *n_mt = nt;
}

// ---------------- compact: deterministic token-ordered pair lists ----------------
__global__ __launch_bounds__(256) void compact_kernel(
    const int* __restrict__ tk_idx, const int* __restrict__ offsets,
    int* __restrict__ pair_token, int* __restrict__ pair_pos, int T)
{
    int e = blockIdx.x;
    int tid = threadIdx.x;
    __shared__ int s[256];
    __shared__ int running;
    if (tid == 0) running = 0;
    __syncthreads();
    int base0 = offsets[e];
    for (int base = 0; base < T; base += 256) {
        int t = base + tid;
        int flag = 0, slot = -1;
        if (t < T) {
            int i0 = tk_idx[2 * t], i1 = tk_idx[2 * t + 1];
            slot = (i0 == e) ? 0 : ((i1 == e) ? 1 : -1);
            flag = (slot >= 0) ? 1 : 0;
        }
        s[tid] = flag;
        __syncthreads();
        for (int d = 1; d < 256; d <<= 1) {
            int v = (tid >= d) ? s[tid - d] : 0;
            __syncthreads();
            s[tid] += v;
            __syncthreads();
        }
        int total = s[255];
        int run = running;
        if (flag) {
            int pos = base0 + run + s[tid] - 1;
            pair_token[pos] = t;
            pair_pos[2 * t + slot] = pos;
        }
        __syncthreads();
        if (tid == 0) running += total;
        __syncthreads();
    }
}

// ---------------- grouped GEMM1 + GLU: h = gelu(x@w1) * (x@v1), bf16 out ----------------
// m97-style single-buffered K-loop. 32KB LDS; default launch_bounds so the
// allocator keeps the 64 acc VGPRs in registers (~88 total -> 5 blocks/CU naturally).
__global__ __launch_bounds__(256) void gemm1_glu_kernel(
    const unsigned short* __restrict__ xbf,
    const unsigned short* __restrict__ w1t, const unsigned short* __restrict__ v1t,
    const int* __restrict__ pair_token, const int* __restrict__ offsets,
    const int* __restrict__ tile_e, const int* __restrict__ tile_row,
    const int* __restrict__ n_mt,
    unsigned short* __restrict__ hbf)
{
    int mt = blockIdx.x;
    if (mt >= *n_mt) return;
    int e = tile_e[mt];
    int row0 = tile_row[mt];
    int end = offsets[e + 1];
    int n0 = blockIdx.y * BN;

    __shared__ __align__(16) unsigned short As[BM * BK];   // 16KB
    __shared__ __align__(16) unsigned short B0s[BN * BK];  // 8KB
    __shared__ __align__(16) unsigned short B1s[BN * BK];  // 8KB

    int tid = threadIdx.x;
    int lane = tid & 63;
    int wid = tid >> 6;
    int wr = wid >> 1, wc = wid & 1;
    int sub = lane >> 3;
    // pre-swizzled source offset within a 128B row-block (constant per lane)
    int srcoff = (((lane & 7) ^ sub) << 4);

    const unsigned short* W0 = w1t + (size_t)e * D_DIM * F_DIM;
    const unsigned short* W1 = v1t + (size_t)e * D_DIM * F_DIM;

    // per-lane global source pointers (advance by 128B per K-step)
    const char* aptr[4];
#pragma unroll
    for (int i = 0; i < 4; ++i) {
        int row = (wid * 4 + i) * 8 + sub;
        int p = row0 + row;
        if (p >= end) p = end - 1;   // garbage rows only feed masked outputs
        aptr[i] = (const char*)(xbf + (size_t)pair_token[p] * D_DIM) + srcoff;
    }
    const char* b0ptr[2];
    const char* b1ptr[2];
#pragma unroll
    for (int i = 0; i < 2; ++i) {
        int n = (wid * 2 + i) * 8 + sub;
        b0ptr[i] = (const char*)(W0 + (size_t)(n0 + n) * D_DIM) + srcoff;
        b1ptr[i] = (const char*)(W1 + (size_t)(n0 + n) * D_DIM) + srcoff;
    }

    f32x4 acc[2][4][2];
#pragma unroll
    for (int a = 0; a < 2; ++a)
#pragma unroll
        for (int m = 0; m < 4; ++m)
#pragma unroll
            for (int n = 0; n < 2; ++n) acc[a][m][n] = (f32x4){0.f, 0.f, 0.f, 0.f};

    auto STAGE = [&]() {
#pragma unroll
        for (int i = 0; i < 4; ++i) {
            gload16(aptr[i], (char*)As + (wid * 4 + i) * 1024);
            aptr[i] += 128;
        }
#pragma unroll
        for (int i = 0; i < 2; ++i) {
            gload16(b0ptr[i], (char*)B0s + (wid * 2 + i) * 1024);
            b0ptr[i] += 128;
            gload16(b1ptr[i], (char*)B1s + (wid * 2 + i) * 1024);
            b1ptr[i] += 128;
        }
    };

    const int NT = D_DIM / BK;
    for (int kt = 0; kt < NT; ++kt) {
        STAGE();
        __syncthreads();                 // vmcnt(0) drain -> LDS ready
#pragma unroll
        for (int kk = 0; kk < 2; ++kk) {
            short8 af[4];
#pragma unroll
            for (int m = 0; m < 4; ++m) {
                int row = wr * 64 + m * 16 + (lane & 15);
                int kb = kk * 64 + (lane >> 4) * 16;
                af[m] = *(const short8*)((char*)As + swz(row, kb));
            }
            short8 bf0[2], bf1[2];
#pragma unroll
            for (int n = 0; n < 2; ++n) {
                int rn = wc * 32 + n * 16 + (lane & 15);
                int kb = kk * 64 + (lane >> 4) * 16;
                bf0[n] = *(const short8*)((char*)B0s + swz(rn, kb));
                bf1[n] = *(const short8*)((char*)B1s + swz(rn, kb));
            }
#pragma unroll
            for (int m = 0; m < 4; ++m)
#pragma unroll
                for (int n = 0; n < 2; ++n) {
                    acc[0][m][n] = __builtin_amdgcn_mfma_f32_16x16x32_bf16(af[m], bf0[n], acc[0][m][n], 0, 0, 0);
                    acc[1][m][n] = __builtin_amdgcn_mfma_f32_16x16x32_bf16(af[m], bf1[n], acc[1][m][n], 0, 0, 0);
                }
        }
        __syncthreads();                 // reads done before next STAGE overwrites
    }
#pragma unroll
    for (int m = 0; m < 4; ++m) {
#pragma unroll
        for (int j = 0; j < 4; ++j) {
            int rl = wr * 64 + m * 16 + (lane >> 4) * 4 + j;
            int p = row0 + rl;
            if (p < end) {
#pragma unroll
                for (int n = 0; n < 2; ++n) {
                    float z1 = acc[0][m][n][j];
                    float z2 = acc[1][m][n][j];
                    float hv = gelu_erf(z1) * z2;
                    hbf[(size_t)p * F_DIM + n0 + wc * 32 + n * 16 + (lane & 15)] = f2bf(hv);
                }
            }
        }
    }
}

// ---------------- grouped GEMM2: y = h @ w2[e], fp32 per-pair out ----------------
// A: hbf [P][F]; B: w2t [E][D][F] bf16. Single-buffered, 24KB LDS.
__global__ __launch_bounds__(256) void gemm2_kernel(
    const unsigned short* __restrict__ hbf,
    const unsigned short* __restrict__ w2t,
    const int* __restrict__ offsets,
    const int* __restrict__ tile_e, const int* __restrict__ tile_row,
    const int* __restrict__ n_mt,
    float* __restrict__ ypair)
{
    int mt = blockIdx.x;
    if (mt >= *n_mt) return;
    int e = tile_e[mt];
    int row0 = tile_row[mt];
    int end = offsets[e + 1];
    int n0 = blockIdx.y * BN;

    __shared__ __align__(16) unsigned short As[BM * BK];  // 16KB
    __shared__ __align__(16) unsigned short Bs[BN * BK];  // 8KB

    int tid = threadIdx.x;
    int lane = tid & 63;
    int wid = tid >> 6;
    int wr = wid >> 1, wc = wid & 1;
    int sub = lane >> 3;
    int srcoff = (((lane & 7) ^ sub) << 4);

    const unsigned short* W = w2t + (size_t)e * D_DIM * F_DIM;

    const char* aptr[4];
#pragma unroll
    for (int i = 0; i < 4; ++i) {
        int row = (wid * 4 + i) * 8 + sub;
        int p = row0 + row;
        if (p >= end) p = end - 1;
        aptr[i] = (const char*)(hbf + (size_t)p * F_DIM) + srcoff;
    }
    const char* bptr[2];
#pragma unroll
    for (int i = 0; i < 2; ++i) {
        int n = (wid * 2 + i) * 8 + sub;
        bptr[i] = (const char*)(W + (size_t)(n0 + n) * F_DIM) + srcoff;
    }

    f32x4 acc[4][2];
#pragma unroll
    for (int m = 0; m < 4; ++m)
#pragma unroll
        for (int n = 0; n < 2; ++n) acc[m][n] = (f32x4){0.f, 0.f, 0.f, 0.f};

    auto STAGE = [&]() {
#pragma unroll
        for (int i = 0; i < 4; ++i) {
            gload16(aptr[i], (char*)As + (wid * 4 + i) * 1024);
            aptr[i] += 128;
        }
#pragma unroll
        for (int i = 0; i < 2; ++i) {
            gload16(bptr[i], (char*)Bs + (wid * 2 + i) * 1024);
            bptr[i] += 128;
        }
    };

    const int NT = F_DIM / BK;
    for (int kt = 0; kt < NT; ++kt) {
        STAGE();
        __syncthreads();
#pragma unroll
        for (int kk = 0; kk < 2; ++kk) {
            short8 af[4];
#pragma unroll
            for (int m = 0; m < 4; ++m) {
                int row = wr * 64 + m * 16 + (lane & 15);
                int kb = kk * 64 + (lane >> 4) * 16;
                af[m] = *(const short8*)((char*)As + swz(row, kb));
            }
            short8 bfr[2];
#pragma unroll
            for (int n = 0; n < 2; ++n) {
                int rn = wc * 32 + n * 16 + (lane & 15);
                int kb = kk * 64 + (lane >> 4) * 16;
                bfr[n] = *(const short8*)((char*)Bs + swz(rn, kb));
            }
#pragma unroll
            for (int m = 0; m < 4; ++m)
#pragma unroll
                for (int n = 0; n < 2; ++n)
                    acc[m][n] = __builtin_amdgcn_mfma_f32_16x16x32_bf16(af[m], bfr[n], acc[m][n], 0, 0, 0);
        }
        __syncthreads();
    }
#pragma unroll
    for (int m = 0; m < 4; ++m) {
#pragma unroll
        for (int j = 0; j < 4; ++j) {
            int rl = wr * 64 + m * 16 + (lane >> 4) * 4 + j;
            int p = row0 + rl;
            if (p < end) {
#pragma unroll
                for (int n = 0; n < 2; ++n)
                    ypair[(size_t)p * D_DIM + n0 + wc * 32 + n * 16 + (lane & 15)] = acc[m][n][j];
            }
        }
    }
}

// ---------------- combine: out = bias + w0*y[p0] + w1*y[p1] ----------------
__global__ __launch_bounds__(256) void combine_kernel(
    const float* __restrict__ ypair, const int* __restrict__ pair_pos,
    const float* __restrict__ tk_w, const float* __restrict__ bias,
    float* __restrict__ out, int total)
{
    int idx = blockIdx.x * 256 + threadIdx.x;
    if (idx >= total) return;
    int t = idx >> 10;
    int d = idx & (D_DIM - 1);
    int p0 = pair_pos[2 * t], p1 = pair_pos[2 * t + 1];
    float r = bias[d] + tk_w[2 * t] * ypair[(size_t)p0 * D_DIM + d]
                      + tk_w[2 * t + 1] * ypair[(size_t)p1 * D_DIM + d];
    out[idx] = r;
}

__global__ void ws_too_small_kernel(float* out, int n) {
    int i = blockIdx.x * 256 + threadIdx.x;
    if (i < n) out[i] = 12345.0f;
}

extern "C" void kernel_launch(void* const* d_in, const int* in_sizes, int n_in,
                              void* d_out, int out_size, void* d_ws, size_t ws_size,
                              hipStream_t stream) {
    const float* x    = (const float*)d_in[0];
    const float* rw   = (const float*)d_in[1];
    const float* w1   = (const float*)d_in[2];
    const float* v1   = (const float*)d_in[3];
    const float* w2   = (const float*)d_in[4];
    const float* bias = (const float*)d_in[5];
    float* out = (float*)d_out;

    int T = in_sizes[0] / D_DIM;      // 4096
    int P = 2 * T;
    int maxMT = P / BM + E_NUM;       // 72

    char* p = (char*)d_ws;
    char* ws_end = p + ws_size;
    auto alloc = [&](size_t bytes) {
        char* r = p;
        p += (bytes + 255) & ~(size_t)255;
        return r;
    };
    unsigned short* xbf   = (unsigned short*)alloc((size_t)T * D_DIM * 2);
    int*   tk_idx     = (int*)alloc((size_t)T * 2 * 4);
    float* tk_w       = (float*)alloc((size_t)T * 2 * 4);
    int*   counts     = (int*)alloc(E_NUM * 4);
    int*   offsets    = (int*)alloc((E_NUM + 1) * 4);
    int*   tile_e     = (int*)alloc(maxMT * 4);
    int*   tile_row   = (int*)alloc(maxMT * 4);
    int*   n_mt       = (int*)alloc(4);
    int*   pair_token = (int*)alloc((size_t)P * 4);
    int*   pair_pos   = (int*)alloc((size_t)P * 4);
    unsigned short* hbf = (unsigned short*)alloc((size_t)P * F_DIM * 2);
    float* ypair      = (float*)alloc((size_t)P * D_DIM * 4);
    unsigned short* w1t = (unsigned short*)alloc((size_t)E_NUM * D_DIM * F_DIM * 2);
    unsigned short* v1t = (unsigned short*)alloc((size_t)E_NUM * D_DIM * F_DIM * 2);
    unsigned short* w2t = (unsigned short*)alloc((size_t)E_NUM * D_DIM * F_DIM * 2);

    if (p > ws_end) {
        ws_too_small_kernel<<<(out_size + 255) / 256, 256, 0, stream>>>(out, out_size);
        return;
    }

    hipMemsetAsync(counts, 0, E_NUM * 4, stream);
    // weight transpose+convert: w1,v1 [E][D][F] -> [E][F][D]; w2 [E][F][D] -> [E][D][F]
    transpose_cvt_kernel<<<dim3(F_DIM / 64, D_DIM / 64, E_NUM), 256, 0, stream>>>(w1, w1t, D_DIM, F_DIM);
    transpose_cvt_kernel<<<dim3(F_DIM / 64, D_DIM / 64, E_NUM), 256, 0, stream>>>(v1, v1t, D_DIM, F_DIM);
    transpose_cvt_kernel<<<dim3(D_DIM / 64, F_DIM / 64, E_NUM), 256, 0, stream>>>(w2, w2t, F_DIM, D_DIM);
    router_kernel<<<T, 64, 0, stream>>>(x, rw, xbf, tk_idx, tk_w, counts);
    scan_kernel<<<1, 64, 0, stream>>>(counts, offsets, tile_e, tile_row, n_mt);
    compact_kernel<<<E_NUM, 256, 0, stream>>>(tk_idx, offsets, pair_token, pair_pos, T);
    gemm1_glu_kernel<<<dim3(maxMT, F_DIM / BN), 256, 0, stream>>>(
        xbf, w1t, v1t, pair_token, offsets, tile_e, tile_row, n_mt, hbf);
    gemm2_kernel<<<dim3(maxMT, D_DIM / BN), 256, 0, stream>>>(
        hbf, w2t, offsets, tile_e, tile_row, n_mt, ypair);
    combine_kernel<<<(T * D_DIM + 255) / 256, 256, 0, stream>>>(
        ypair, pair_pos, tk_w, bias, out, T * D_DIM);
}

// Round 6
// 456.233 us; speedup vs baseline: 2.3121x; 1.0565x over previous
//
#include <hip/hip_runtime.h>
#include <hip/hip_bf16.h>
#include <math.h>

#define D_DIM 1024
#define F_DIM 2816
#define E_NUM 8

#define BM 128
#define BK 64

typedef __attribute__((ext_vector_type(4))) float f32x4;
typedef __attribute__((ext_vector_type(8))) short short8;

__device__ __forceinline__ unsigned short f2bf(float f) {
    unsigned u = __float_as_uint(f);
    u = (u + 0x7FFFu + ((u >> 16) & 1u)) >> 16;
    return (unsigned short)u;
}

__device__ __forceinline__ float gelu_erf(float z) {
    return 0.5f * z * (1.0f + erff(z * 0.70710678118654752f));
}

// XOR swizzle on the LDS READ side: 128B rows, 16B blocks permuted by row&7.
// WRITE side achieves the same layout via pre-swizzled GLOBAL source addresses
// fed to global_load_lds (LDS dest stays linear).
__device__ __forceinline__ int swz(int row, int kb) {
    return row * 128 + (kb ^ ((row & 7) << 4));
}

__device__ __forceinline__ uint4 pack8(const unsigned short* h) {
    uint4 r;
    r.x = (unsigned)h[0] | ((unsigned)h[1] << 16);
    r.y = (unsigned)h[2] | ((unsigned)h[3] << 16);
    r.z = (unsigned)h[4] | ((unsigned)h[5] << 16);
    r.w = (unsigned)h[6] | ((unsigned)h[7] << 16);
    return r;
}

// async global->LDS, 16B per lane; lds must be wave-uniform, g is per-lane
__device__ __forceinline__ void gload16(const void* g, void* l) {
    __builtin_amdgcn_global_load_lds(
        (const __attribute__((address_space(1))) unsigned int*)g,
        (__attribute__((address_space(3))) unsigned int*)l,
        16, 0, 0);
}

// ---------------- weight transpose + fp32->bf16 convert ----------------
// src [E][R][C] fp32 -> dst [E][C][R] bf16. grid (C/64, R/64, E), 256 thr.
__global__ __launch_bounds__(256) void transpose_cvt_kernel(
    const float* __restrict__ src, unsigned short* __restrict__ dst, int R, int C)
{
    __shared__ float tile[64][65];
    int e = blockIdx.z;
    const float* s = src + (size_t)e * R * C;
    unsigned short* d = dst + (size_t)e * R * C;
    int c0 = blockIdx.x * 64;
    int r0 = blockIdx.y * 64;
    int tid = threadIdx.x;
#pragma unroll
    for (int i = 0; i < 4; ++i) {
        int idx = tid + 256 * i;
        int r = idx >> 4, cc = (idx & 15) * 4;
        float4 v = *(const float4*)(s + (size_t)(r0 + r) * C + c0 + cc);
        tile[r][cc] = v.x; tile[r][cc + 1] = v.y; tile[r][cc + 2] = v.z; tile[r][cc + 3] = v.w;
    }
    __syncthreads();
#pragma unroll
    for (int i = 0; i < 2; ++i) {
        int idx = tid + 256 * i;
        int c = idx >> 3, rr = (idx & 7) * 8;
        unsigned short h[8];
#pragma unroll
        for (int j = 0; j < 8; ++j) h[j] = f2bf(tile[rr + j][c]);
        *(uint4*)(d + (size_t)(c0 + c) * R + r0 + rr) = pack8(h);
    }
}

// ---------------- router: scores, softmax, top-2, x->bf16 ----------------
__global__ __launch_bounds__(64) void router_kernel(
    const float* __restrict__ x, const float* __restrict__ rw,
    unsigned short* __restrict__ xbf, int* __restrict__ tk_idx,
    float* __restrict__ tk_w, int* __restrict__ counts)
{
    int t = blockIdx.x;
    int lane = threadIdx.x;
    const float* xr = x + (size_t)t * D_DIM;
    float acc[E_NUM];
#pragma unroll
    for (int e = 0; e < E_NUM; ++e) acc[e] = 0.f;
#pragma unroll
    for (int i = 0; i < D_DIM / 64; ++i) {
        int d = lane + 64 * i;
        float xv = xr[d];
        xbf[(size_t)t * D_DIM + d] = f2bf(xv);
        const float* rp = rw + (size_t)d * E_NUM;
#pragma unroll
        for (int e = 0; e < E_NUM; ++e) acc[e] += xv * rp[e];
    }
#pragma unroll
    for (int e = 0; e < E_NUM; ++e) {
#pragma unroll
        for (int s = 32; s > 0; s >>= 1) acc[e] += __shfl_xor(acc[e], s, 64);
    }
    float mx = acc[0];
#pragma unroll
    for (int e = 1; e < E_NUM; ++e) mx = fmaxf(mx, acc[e]);
    float p[E_NUM], se = 0.f;
#pragma unroll
    for (int e = 0; e < E_NUM; ++e) { p[e] = expf(acc[e] - mx); se += p[e]; }
    float inv = 1.f / se;
    int e1 = 0;
#pragma unroll
    for (int e = 1; e < E_NUM; ++e) if (p[e] > p[e1]) e1 = e;
    int e2 = (e1 == 0) ? 1 : 0;
#pragma unroll
    for (int e = 0; e < E_NUM; ++e) if (e != e1 && p[e] > p[e2]) e2 = e;
    if (lane == 0) {
        tk_idx[2 * t] = e1; tk_idx[2 * t + 1] = e2;
        tk_w[2 * t] = p[e1] * inv; tk_w[2 * t + 1] = p[e2] * inv;
        atomicAdd(&counts[e1], 1);
        atomicAdd(&counts[e2], 1);
    }
}

// ---------------- scan: offsets + tile map ----------------
__global__ void scan_kernel(const int* __restrict__ counts, int* __restrict__ offsets,
                            int* __restrict__ tile_e, int* __restrict__ tile_row,
                            int* __restrict__ n_mt)
{
    if (threadIdx.x != 0) return;
    int off = 0, nt = 0;
    for (int e = 0; e < E_NUM; ++e) {
        offsets[e] = off;
        int ne = counts[e];
        int nti = (ne + BM - 1) / BM;
        for (int i = 0; i < nti; ++i) { tile_e[nt] = e; tile_row[nt] = off + i * BM; ++nt; }
        off += ne;
    }
    offsets[E_NUM] = off;
    *n_mt = nt;
}

// ---------------- compact: deterministic token-ordered pair lists ----------------
__global__ __launch_bounds__(256) void compact_kernel(
    const int* __restrict__ tk_idx, const int* __restrict__ offsets,
    int* __restrict__ pair_token, int* __restrict__ pair_pos, int T)
{
    int e = blockIdx.x;
    int tid = threadIdx.x;
    __shared__ int s[256];
    __shared__ int running;
    if (tid == 0) running = 0;
    __syncthreads();
    int base0 = offsets[e];
    for (int base = 0; base < T; base += 256) {
        int t = base + tid;
        int flag = 0, slot = -1;
        if (t < T) {
            int i0 = tk_idx[2 * t], i1 = tk_idx[2 * t + 1];
            slot = (i0 == e) ? 0 : ((i1 == e) ? 1 : -1);
            flag = (slot >= 0) ? 1 : 0;
        }
        s[tid] = flag;
        __syncthreads();
        for (int d = 1; d < 256; d <<= 1) {
            int v = (tid >= d) ? s[tid - d] : 0;
            __syncthreads();
            s[tid] += v;
            __syncthreads();
        }
        int total = s[255];
        int run = running;
        if (flag) {
            int pos = base0 + run + s[tid] - 1;
            pair_token[pos] = t;
            pair_pos[2 * t + slot] = pos;
        }
        __syncthreads();
        if (tid == 0) running += total;
        __syncthreads();
    }
}

// ---------------- grouped GEMM1 + GLU: h = gelu(x@w1) * (x@v1), bf16 out ----------------
// 512 threads / 8 waves; per-wave 32x32 output per gemm -> acc only 32 VGPRs,
// so ~5 waves/SIMD fit (was 3 at 4-wave/64-acc). Tile & LDS identical to r5.
__global__ __launch_bounds__(512) void gemm1_glu_kernel(
    const unsigned short* __restrict__ xbf,
    const unsigned short* __restrict__ w1t, const unsigned short* __restrict__ v1t,
    const int* __restrict__ pair_token, const int* __restrict__ offsets,
    const int* __restrict__ tile_e, const int* __restrict__ tile_row,
    const int* __restrict__ n_mt,
    unsigned short* __restrict__ hbf)
{
    int mt = blockIdx.x;
    if (mt >= *n_mt) return;
    int e = tile_e[mt];
    int row0 = tile_row[mt];
    int end = offsets[e + 1];
    int n0 = blockIdx.y * 64;

    __shared__ __align__(16) unsigned short As[BM * BK];   // 16KB
    __shared__ __align__(16) unsigned short B0s[64 * BK];  // 8KB
    __shared__ __align__(16) unsigned short B1s[64 * BK];  // 8KB

    int tid = threadIdx.x;
    int lane = tid & 63;
    int wid = tid >> 6;            // 0..7
    int wr = wid >> 1, wc = wid & 1;   // wave grid 4(M) x 2(N)
    int sub = lane >> 3;
    int srcoff = (((lane & 7) ^ sub) << 4);

    const unsigned short* W0 = w1t + (size_t)e * D_DIM * F_DIM;
    const unsigned short* W1 = v1t + (size_t)e * D_DIM * F_DIM;

    // A: 16 row-blocks of 8 rows; this wave owns blocks wid*2+i
    const char* aptr[2];
#pragma unroll
    for (int i = 0; i < 2; ++i) {
        int row = (wid * 2 + i) * 8 + sub;
        int p = row0 + row;
        if (p >= end) p = end - 1;   // garbage rows only feed masked outputs
        aptr[i] = (const char*)(xbf + (size_t)pair_token[p] * D_DIM) + srcoff;
    }
    // B: 8 row-blocks each; this wave owns block wid
    int nb = wid * 8 + sub;
    const char* b0ptr = (const char*)(W0 + (size_t)(n0 + nb) * D_DIM) + srcoff;
    const char* b1ptr = (const char*)(W1 + (size_t)(n0 + nb) * D_DIM) + srcoff;

    f32x4 acc[2][2][2];
#pragma unroll
    for (int a = 0; a < 2; ++a)
#pragma unroll
        for (int m = 0; m < 2; ++m)
#pragma unroll
            for (int n = 0; n < 2; ++n) acc[a][m][n] = (f32x4){0.f, 0.f, 0.f, 0.f};

    auto STAGE = [&]() {
#pragma unroll
        for (int i = 0; i < 2; ++i) {
            gload16(aptr[i], (char*)As + (wid * 2 + i) * 1024);
            aptr[i] += 128;
        }
        gload16(b0ptr, (char*)B0s + wid * 1024);
        b0ptr += 128;
        gload16(b1ptr, (char*)B1s + wid * 1024);
        b1ptr += 128;
    };

    const int NT = D_DIM / BK;
    for (int kt = 0; kt < NT; ++kt) {
        STAGE();
        __syncthreads();                 // vmcnt(0) drain -> LDS ready
#pragma unroll
        for (int kk = 0; kk < 2; ++kk) {
            int kb = kk * 64 + (lane >> 4) * 16;
            short8 af[2];
#pragma unroll
            for (int m = 0; m < 2; ++m) {
                int row = wr * 32 + m * 16 + (lane & 15);
                af[m] = *(const short8*)((char*)As + swz(row, kb));
            }
            short8 bf0[2], bf1[2];
#pragma unroll
            for (int n = 0; n < 2; ++n) {
                int rn = wc * 32 + n * 16 + (lane & 15);
                bf0[n] = *(const short8*)((char*)B0s + swz(rn, kb));
                bf1[n] = *(const short8*)((char*)B1s + swz(rn, kb));
            }
#pragma unroll
            for (int m = 0; m < 2; ++m)
#pragma unroll
                for (int n = 0; n < 2; ++n) {
                    acc[0][m][n] = __builtin_amdgcn_mfma_f32_16x16x32_bf16(af[m], bf0[n], acc[0][m][n], 0, 0, 0);
                    acc[1][m][n] = __builtin_amdgcn_mfma_f32_16x16x32_bf16(af[m], bf1[n], acc[1][m][n], 0, 0, 0);
                }
        }
        __syncthreads();                 // reads done before next STAGE overwrites
    }
#pragma unroll
    for (int m = 0; m < 2; ++m) {
#pragma unroll
        for (int j = 0; j < 4; ++j) {
            int rl = wr * 32 + m * 16 + (lane >> 4) * 4 + j;
            int p = row0 + rl;
            if (p < end) {
#pragma unroll
                for (int n = 0; n < 2; ++n) {
                    float z1 = acc[0][m][n][j];
                    float z2 = acc[1][m][n][j];
                    float hv = gelu_erf(z1) * z2;
                    hbf[(size_t)p * F_DIM + n0 + wc * 32 + n * 16 + (lane & 15)] = f2bf(hv);
                }
            }
        }
    }
}

// ---------------- grouped GEMM2: y = h @ w2[e], fp32 per-pair out ----------------
// 512 threads / 8 waves, BN=128 (halves N-strips -> halves A re-reads).
// A: hbf [P][F]; B: w2t [E][D][F] bf16. LDS 32KB.
__global__ __launch_bounds__(512) void gemm2_kernel(
    const unsigned short* __restrict__ hbf,
    const unsigned short* __restrict__ w2t,
    const int* __restrict__ offsets,
    const int* __restrict__ tile_e, const int* __restrict__ tile_row,
    const int* __restrict__ n_mt,
    float* __restrict__ ypair)
{
    int mt = blockIdx.x;
    if (mt >= *n_mt) return;
    int e = tile_e[mt];
    int row0 = tile_row[mt];
    int end = offsets[e + 1];
    int n0 = blockIdx.y * 128;

    __shared__ __align__(16) unsigned short As[BM * BK];   // 16KB
    __shared__ __align__(16) unsigned short Bs[128 * BK];  // 16KB

    int tid = threadIdx.x;
    int lane = tid & 63;
    int wid = tid >> 6;                 // 0..7
    int wr = wid >> 2, wc = wid & 3;    // wave grid 2(M) x 4(N)
    int sub = lane >> 3;
    int srcoff = (((lane & 7) ^ sub) << 4);

    const unsigned short* W = w2t + (size_t)e * D_DIM * F_DIM;

    const char* aptr[2];
#pragma unroll
    for (int i = 0; i < 2; ++i) {
        int row = (wid * 2 + i) * 8 + sub;
        int p = row0 + row;
        if (p >= end) p = end - 1;
        aptr[i] = (const char*)(hbf + (size_t)p * F_DIM) + srcoff;
    }
    const char* bptr[2];
#pragma unroll
    for (int i = 0; i < 2; ++i) {
        int n = (wid * 2 + i) * 8 + sub;
        bptr[i] = (const char*)(W + (size_t)(n0 + n) * F_DIM) + srcoff;
    }

    f32x4 acc[4][2];
#pragma unroll
    for (int m = 0; m < 4; ++m)
#pragma unroll
        for (int n = 0; n < 2; ++n) acc[m][n] = (f32x4){0.f, 0.f, 0.f, 0.f};

    auto STAGE = [&]() {
#pragma unroll
        for (int i = 0; i < 2; ++i) {
            gload16(aptr[i], (char*)As + (wid * 2 + i) * 1024);
            aptr[i] += 128;
            gload16(bptr[i], (char*)Bs + (wid * 2 + i) * 1024);
            bptr[i] += 128;
        }
    };

    const int NT = F_DIM / BK;
    for (int kt = 0; kt < NT; ++kt) {
        STAGE();
        __syncthreads();
#pragma unroll
        for (int kk = 0; kk < 2; ++kk) {
            int kb = kk * 64 + (lane >> 4) * 16;
            short8 af[4];
#pragma unroll
            for (int m = 0; m < 4; ++m) {
                int row = wr * 64 + m * 16 + (lane & 15);
                af[m] = *(const short8*)((char*)As + swz(row, kb));
            }
            short8 bfr[2];
#pragma unroll
            for (int n = 0; n < 2; ++n) {
                int rn = wc * 32 + n * 16 + (lane & 15);
                bfr[n] = *(const short8*)((char*)Bs + swz(rn, kb));
            }
#pragma unroll
            for (int m = 0; m < 4; ++m)
#pragma unroll
                for (int n = 0; n < 2; ++n)
                    acc[m][n] = __builtin_amdgcn_mfma_f32_16x16x32_bf16(af[m], bfr[n], acc[m][n], 0, 0, 0);
        }
        __syncthreads();
    }
#pragma unroll
    for (int m = 0; m < 4; ++m) {
#pragma unroll
        for (int j = 0; j < 4; ++j) {
            int rl = wr * 64 + m * 16 + (lane >> 4) * 4 + j;
            int p = row0 + rl;
            if (p < end) {
#pragma unroll
                for (int n = 0; n < 2; ++n)
                    ypair[(size_t)p * D_DIM + n0 + wc * 32 + n * 16 + (lane & 15)] = acc[m][n][j];
            }
        }
    }
}

// ---------------- combine: out = bias + w0*y[p0] + w1*y[p1] ----------------
__global__ __launch_bounds__(256) void combine_kernel(
    const float* __restrict__ ypair, const int* __restrict__ pair_pos,
    const float* __restrict__ tk_w, const float* __restrict__ bias,
    float* __restrict__ out, int total)
{
    int idx = blockIdx.x * 256 + threadIdx.x;
    if (idx >= total) return;
    int t = idx >> 10;
    int d = idx & (D_DIM - 1);
    int p0 = pair_pos[2 * t], p1 = pair_pos[2 * t + 1];
    float r = bias[d] + tk_w[2 * t] * ypair[(size_t)p0 * D_DIM + d]
                      + tk_w[2 * t + 1] * ypair[(size_t)p1 * D_DIM + d];
    out[idx] = r;
}

__global__ void ws_too_small_kernel(float* out, int n) {
    int i = blockIdx.x * 256 + threadIdx.x;
    if (i < n) out[i] = 12345.0f;
}

extern "C" void kernel_launch(void* const* d_in, const int* in_sizes, int n_in,
                              void* d_out, int out_size, void* d_ws, size_t ws_size,
                              hipStream_t stream) {
    const float* x    = (const float*)d_in[0];
    const float* rw   = (const float*)d_in[1];
    const float* w1   = (const float*)d_in[2];
    const float* v1   = (const float*)d_in[3];
    const float* w2   = (const float*)d_in[4];
    const float* bias = (const float*)d_in[5];
    float* out = (float*)d_out;

    int T = in_sizes[0] / D_DIM;      // 4096
    int P = 2 * T;
    int maxMT = P / BM + E_NUM;       // 72

    char* p = (char*)d_ws;
    char* ws_end = p + ws_size;
    auto alloc = [&](size_t bytes) {
        char* r = p;
        p += (bytes + 255) & ~(size_t)255;
        return r;
    };
    unsigned short* xbf   = (unsigned short*)alloc((size_t)T * D_DIM * 2);
    int*   tk_idx     = (int*)alloc((size_t)T * 2 * 4);
    float* tk_w       = (float*)alloc((size_t)T * 2 * 4);
    int*   counts     = (int*)alloc(E_NUM * 4);
    int*   offsets    = (int*)alloc((E_NUM + 1) * 4);
    int*   tile_e     = (int*)alloc(maxMT * 4);
    int*   tile_row   = (int*)alloc(maxMT * 4);
    int*   n_mt       = (int*)alloc(4);
    int*   pair_token = (int*)alloc((size_t)P * 4);
    int*   pair_pos   = (int*)alloc((size_t)P * 4);
    unsigned short* hbf = (unsigned short*)alloc((size_t)P * F_DIM * 2);
    float* ypair      = (float*)alloc((size_t)P * D_DIM * 4);
    unsigned short* w1t = (unsigned short*)alloc((size_t)E_NUM * D_DIM * F_DIM * 2);
    unsigned short* v1t = (unsigned short*)alloc((size_t)E_NUM * D_DIM * F_DIM * 2);
    unsigned short* w2t = (unsigned short*)alloc((size_t)E_NUM * D_DIM * F_DIM * 2);

    if (p > ws_end) {
        ws_too_small_kernel<<<(out_size + 255) / 256, 256, 0, stream>>>(out, out_size);
        return;
    }

    hipMemsetAsync(counts, 0, E_NUM * 4, stream);
    // weight transpose+convert: w1,v1 [E][D][F] -> [E][F][D]; w2 [E][F][D] -> [E][D][F]
    transpose_cvt_kernel<<<dim3(F_DIM / 64, D_DIM / 64, E_NUM), 256, 0, stream>>>(w1, w1t, D_DIM, F_DIM);
    transpose_cvt_kernel<<<dim3(F_DIM / 64, D_DIM / 64, E_NUM), 256, 0, stream>>>(v1, v1t, D_DIM, F_DIM);
    transpose_cvt_kernel<<<dim3(D_DIM / 64, F_DIM / 64, E_NUM), 256, 0, stream>>>(w2, w2t, F_DIM, D_DIM);
    router_kernel<<<T, 64, 0, stream>>>(x, rw, xbf, tk_idx, tk_w, counts);
    scan_kernel<<<1, 64, 0, stream>>>(counts, offsets, tile_e, tile_row, n_mt);
    compact_kernel<<<E_NUM, 256, 0, stream>>>(tk_idx, offsets, pair_token, pair_pos, T);
    gemm1_glu_kernel<<<dim3(maxMT, F_DIM / 64), 512, 0, stream>>>(
        xbf, w1t, v1t, pair_token, offsets, tile_e, tile_row, n_mt, hbf);
    gemm2_kernel<<<dim3(maxMT, D_DIM / 128), 512, 0, stream>>>(
        hbf, w2t, offsets, tile_e, tile_row, n_mt, ypair);
    combine_kernel<<<(T * D_DIM + 255) / 256, 256, 0, stream>>>(
        ypair, pair_pos, tk_w, bias, out, T * D_DIM);
}